// Round 9
// baseline (205.796 us; speedup 1.0000x reference)
//
#include <hip/hip_runtime.h>
#include <hip/hip_bf16.h>

#define NJ 24
#define NV 6890
#define NB 1024
#define V3 (NV*3)         // 20670 floats per batch in out
#define JTR_OFF (NB*NV*3)

typedef __attribute__((ext_vector_type(8))) short bf16x8;
typedef __attribute__((ext_vector_type(4))) float f32x4;
typedef float f4u __attribute__((ext_vector_type(4), aligned(4)));

__constant__ int c_par[NJ] = {-1,0,0,0,1,2,3,4,5,6,7,8,9,9,9,12,13,14,16,17,18,19,20,21};

// ---------------------------------------------------------------------------
// kpre: fused preprocessing — one dispatch replaces kpack + kwB + k0 + memset.
//   bid <  2268 : kpack  (pdBsw build, 580608 chunks)
//   bid <  2376 : kwB    (wtsB build, 27648 chunks)
//   bid <  2400 : k0     (joint regressor fold; 1 block per joint, full
//                         v-range, NO atomics/memset — block exclusively
//                         owns Jc[j*33..])
// ---------------------------------------------------------------------------
__global__ void kpre(const float* __restrict__ pdirs, const float* __restrict__ shdirs,
                     const float* __restrict__ vtempl, const float* __restrict__ wts,
                     const float* __restrict__ Jreg,
                     __hip_bfloat16* __restrict__ pdBsw, __hip_bfloat16* __restrict__ wtsB,
                     float* __restrict__ Jc)
{
    __shared__ float red[4][33];
    int bid = blockIdx.x;

    if (bid < 2268) {
        // ---- kpack: chunk cid = (((vtile*7+kt)*3+c)*4+kq)*64+v64, 8 k each
        int cid = bid * 256 + threadIdx.x;   // < 580608
        int v64 = cid & 63;
        int t = cid >> 6;
        int kq = t & 3; t >>= 2;
        int c = t % 3; t /= 3;
        int kt = t % 7;
        int vt = t / 7;
        int v = vt * 64 + v64;

        ushort tmp[8] __attribute__((aligned(16)));
#pragma unroll
        for (int j = 0; j < 8; ++j) {
            int k = kt * 32 + kq * 8 + j;
            float val = 0.0f;
            if (v < NV) {
                if (k < 207)       val = pdirs[(v * 3 + c) * 207 + k];
                else if (k < 217)  val = shdirs[(v * 3 + c) * 10 + (k - 207)];
                else if (k == 217) val = vtempl[v * 3 + c];
            }
            __hip_bfloat16 h = __float2bfloat16(val);
            tmp[j] = *(ushort*)&h;
        }
        ((float4*)pdBsw)[cid] = *(const float4*)tmp;
    } else if (bid < 2376) {
        // ---- kwB: chunk = (vtile*4 + kq)*64 + v64, 8 j each, K=32
        int t = (bid - 2268) * 256 + threadIdx.x;     // < 27648
        int v64 = t & 63;
        int kq = (t >> 6) & 3;
        int vt = t >> 8;
        int v = vt * 64 + v64;

        ushort tmp[8] __attribute__((aligned(16)));
#pragma unroll
        for (int j8 = 0; j8 < 8; ++j8) {
            int j = kq * 8 + j8;
            float val = (v < NV && j < NJ) ? wts[v * NJ + j] : 0.0f;
            __hip_bfloat16 h = __float2bfloat16(val);
            tmp[j8] = *(ushort*)&h;
        }
        ((float4*)wtsB)[t] = *(const float4*)tmp;
    } else {
        // ---- k0: Jc[j][c][s] — s<10: Jreg@shapedirs, s=10: Jreg@tmpl
        int j = bid - 2376;      // 0..23
        float acc[33];
#pragma unroll
        for (int i = 0; i < 33; ++i) acc[i] = 0.0f;

        for (int v = threadIdx.x; v < NV; v += 256) {
            float r = Jreg[j * NV + v];
#pragma unroll
            for (int c = 0; c < 3; ++c) {
                acc[c * 11 + 10] += r * vtempl[v * 3 + c];
                const float* sd = &shdirs[(v * 3 + c) * 10];
#pragma unroll
                for (int s = 0; s < 10; ++s) acc[c * 11 + s] += r * sd[s];
            }
        }
#pragma unroll
        for (int i = 0; i < 33; ++i) {
            float x = acc[i];
            for (int o = 32; o > 0; o >>= 1) x += __shfl_down(x, o, 64);
            acc[i] = x;
        }
        int w = threadIdx.x >> 6, l = threadIdx.x & 63;
        if (l == 0) {
#pragma unroll
            for (int i = 0; i < 33; ++i) red[w][i] = acc[i];
        }
        __syncthreads();
        if (threadIdx.x < 33) {
            Jc[j * 33 + threadIdx.x] = red[0][threadIdx.x] + red[1][threadIdx.x] +
                                       red[2][threadIdx.x] + red[3][threadIdx.x];
        }
    }
}

// ---------------------------------------------------------------------------
// k1: Rodrigues, A (bf16, swizzled), th_j, kinematic chain, G2B (bf16,
// A-operand swizzled, 12 components), th_jtr. One wave/batch, 4 batches/block.
// ABsw chunk: ((btile*7 + kt)*4 + kq)*64 + b64, 8 k each.
// G2B[mc] chunk: ((btile*4 + jq)*64 + b64)*8 + j7, mc stride 32768 elements.
// ---------------------------------------------------------------------------
__device__ __forceinline__ void writeA(__hip_bfloat16* ABsw, int b, int k, float val)
{
    int btile = b >> 6, b6 = b & 63, kt = k >> 5, kq = (k >> 3) & 3, j = k & 7;
    __hip_bfloat16 h = __float2bfloat16(val);
    ABsw[((((btile * 7) + kt) * 4 + kq) * 64 + b6) * 8 + j] = h;
}

__global__ void k1(const float* __restrict__ pose, const float* __restrict__ betas,
                   const float* __restrict__ trans, const float* __restrict__ Jc,
                   __hip_bfloat16* __restrict__ ABsw, __hip_bfloat16* __restrict__ G2B,
                   float* __restrict__ out)
{
    __shared__ float rots[4][NJ][9];
    __shared__ float thj [4][NJ][3];
    __shared__ float res [4][NJ][16];

    int w = threadIdx.x >> 6;
    int l = threadIdx.x & 63;
    int b = blockIdx.x * 4 + w;

    if (l < NJ) {
        int j = l;
        float ax = pose[b * 72 + j * 3 + 0];
        float ay = pose[b * 72 + j * 3 + 1];
        float az = pose[b * 72 + j * 3 + 2];
        float theta = sqrtf(ax * ax + ay * ay + az * az + 1e-8f);
        float inv = 1.0f / theta;
        float kx = ax * inv, ky = ay * inv, kz = az * inv;
        float c = cosf(theta), s = sinf(theta), mc = 1.0f - c;
        float R[9];
        R[0] = 1.0f - mc * (ky * ky + kz * kz);
        R[1] = -s * kz + mc * (kx * ky);
        R[2] =  s * ky + mc * (kx * kz);
        R[3] =  s * kz + mc * (kx * ky);
        R[4] = 1.0f - mc * (kx * kx + kz * kz);
        R[5] = -s * kx + mc * (ky * kz);
        R[6] = -s * ky + mc * (kx * kz);
        R[7] =  s * kx + mc * (ky * kz);
        R[8] = 1.0f - mc * (kx * kx + ky * ky);
#pragma unroll
        for (int e = 0; e < 9; ++e) rots[w][j][e] = R[e];
        if (j >= 1) {
            int base = (j - 1) * 9;
#pragma unroll
            for (int e = 0; e < 9; ++e) {
                float val = R[e] - ((e == 0 || e == 4 || e == 8) ? 1.0f : 0.0f);
                writeA(ABsw, b, base + e, val);
            }
        }
#pragma unroll
        for (int c3 = 0; c3 < 3; ++c3) {
            float acc = Jc[(j * 3 + c3) * 11 + 10];
#pragma unroll
            for (int s10 = 0; s10 < 10; ++s10)
                acc += Jc[(j * 3 + c3) * 11 + s10] * betas[b * 10 + s10];
            thj[w][j][c3] = acc;
        }
    } else if (l < 41) {
        int k = 207 + (l - 24);
        float val;
        if (l < 34)       val = betas[b * 10 + (l - 24)];
        else if (l == 34) val = 1.0f;
        else              val = 0.0f;
        writeA(ABsw, b, k, val);
    }
    __syncthreads();

    if (l < 16) {
        int m = l >> 2, n = l & 3;
        float v;
        if (m < 3) v = (n < 3) ? rots[w][0][m * 3 + n] : thj[w][0][m];
        else       v = (n == 3) ? 1.0f : 0.0f;
        res[w][0][l] = v;
    }
    __syncthreads();
#pragma unroll
    for (int i = 1; i < NJ; ++i) {
        int p = c_par[i];
        if (l < 16) {
            int m = l >> 2, n = l & 3;
            float acc = 0.0f;
#pragma unroll
            for (int k3 = 0; k3 < 3; ++k3) {
                float relkn = (n < 3) ? rots[w][i][k3 * 3 + n]
                                      : (thj[w][i][k3] - thj[w][p][k3]);
                acc += res[w][p][m * 4 + k3] * relkn;
            }
            if (n == 3) acc += res[w][p][m * 4 + 3];
            res[w][i][l] = acc;
        }
        __syncthreads();
    }

    if (l < NJ) {
        int j = l;
#pragma unroll
        for (int c3 = 0; c3 < 3; ++c3)
            out[JTR_OFF + b * 72 + j * 3 + c3] = res[w][j][c3 * 4 + 3] + trans[b * 3 + c3];
    }
    // G2B: 12 components mc = m*4+n, K=32 (j=24..31 zero), bf16 A-operand swizzle
    for (int k = l; k < 384; k += 64) {
        int mc = k >> 5, j = k & 31;
        int m = mc >> 2, n = mc & 3;
        float v = 0.0f;
        if (j < NJ) {
            if (n < 3) v = res[w][j][m * 4 + n];
            else v = res[w][j][m * 4 + 3] - (res[w][j][m * 4 + 0] * thj[w][j][0] +
                                             res[w][j][m * 4 + 1] * thj[w][j][1] +
                                             res[w][j][m * 4 + 2] * thj[w][j][2]);
        }
        __hip_bfloat16 h = __float2bfloat16(v);
        G2B[mc * 32768 + ((((b >> 6) * 4) + (j >> 3)) * 64 + (b & 63)) * 8 + (j & 7)] = h;
    }
}

// ---------------------------------------------------------------------------
// helper: 16B global -> LDS direct (DMA), wave-uniform LDS base + lane*16.
// ---------------------------------------------------------------------------
__device__ __forceinline__ void gld16(const void* g, void* l)
{
    __builtin_amdgcn_global_load_lds(
        (const __attribute__((address_space(1))) void*)g,
        (__attribute__((address_space(3))) void*)l, 16, 0, 0);
}

// ---------------------------------------------------------------------------
// k2g: fused pose-GEMM + MFMA blend.  A = batches (M), B = verts (N).
// Block: 64b x 64v x 3c, 4 waves (2x2), K-loop 7 x 32, mfma 16x16x32 bf16.
// v8: round-8 structure + NON-TEMPORAL readback stores. Evidence: round-4
// FETCH jumped 25->40 MB with the dense-store epilogue — consistent with
// partial-line RMW read-allocate at the misaligned row edges (b*V3*4 = 56
// mod 64). nt bit -> streaming store, no read-allocate. If the RMW theory
// holds: FETCH back to ~25 MB and the store stream stops costing read BW.
// K-loop (kept, neutral): double-buffered global_load_lds + raw s_barrier +
// counted vmcnt(4) — next tile's loads stay in flight across barriers.
// XCD remap (T1, kept, +5 us): lin=(wgid&7)*216+(wgid>>3).
// Store path (kept): blend(+trans) -> [32][204] f32 LDS tile, 2 passes;
// each 768B batch-row stored by 48 lanes x dwordx4 per instruction.
// ---------------------------------------------------------------------------
__launch_bounds__(256, 3)
__global__ void k2g(const __hip_bfloat16* __restrict__ pdBsw,
                    const __hip_bfloat16* __restrict__ ABsw,
                    const __hip_bfloat16* __restrict__ G2B,
                    const __hip_bfloat16* __restrict__ wtsB,
                    const float* __restrict__ trans,
                    float* __restrict__ outp)
{
    // 2 x 16KB double-buffer (As 12KB + Bs 4KB each); epilogue outs tile
    // ([32][204] f32 = 26112B) overlays after the K-loop's final barrier.
    __shared__ __align__(16) char smem[2 * 16384];
    float* outs = (float*)smem;

    int tid = threadIdx.x;
    // XCD-aware remap: 1728 blocks = 8 XCDs x 216.
    int wgid = blockIdx.y * 108 + blockIdx.x;
    int lin  = (wgid & 7) * 216 + (wgid >> 3);
    int vtile = lin >> 4;        // 0..107
    int btile = lin & 15;        // 0..15
    int wid = tid >> 6, lane = tid & 63;
    int waveb = wid & 1, wavev = wid >> 1;
    int kq = lane >> 4, l15 = lane & 15;

    // stage one K-tile (As: 768 chunks, Bs: 256 chunks of 16B) into buf kb.
    auto stage = [&](int kb, int kt) {
        char* dst = smem + kb * 16384;
        const ushort* gA = (const ushort*)pdBsw + (size_t)(vtile * 7 + kt) * 6144;
        const ushort* gB = (const ushort*)ABsw  + (size_t)(btile * 7 + kt) * 2048;
#pragma unroll
        for (int i = 0; i < 3; ++i)
            gld16(gA + (i * 256 + wid * 64 + lane) * 8, dst + i * 4096 + wid * 1024);
        gld16(gB + (wid * 64 + lane) * 8, dst + 12288 + wid * 1024);
    };

    f32x4 acc[3][2][2] = {};   // [c][mi=b-sub][ni=v-sub]

    int aoff = (kq * 64 + waveb * 32 + l15) * 8;      // batch frag (Bs) + mi*128
    int boff = (kq * 64 + wavev * 32 + l15) * 8;      // vert frag (As) + ni*128 + c*2048

    stage(0, 0);
    for (int kt = 0; kt < 7; ++kt) {
        if (kt < 6) {
            stage((kt + 1) & 1, kt + 1);
            asm volatile("s_waitcnt vmcnt(4)" ::: "memory");  // cur tile landed
        } else {
            asm volatile("s_waitcnt vmcnt(0)" ::: "memory");
        }
        __builtin_amdgcn_s_barrier();
        asm volatile("" ::: "memory");

        const ushort* As = (const ushort*)(smem + (kt & 1) * 16384);
        const ushort* Bs = As + 6144;   // +12288 bytes

        bf16x8 af[2];
#pragma unroll
        for (int mi = 0; mi < 2; ++mi)
            af[mi] = *(const bf16x8*)&Bs[aoff + mi * 128];
#pragma unroll
        for (int c = 0; c < 3; ++c) {
            bf16x8 bfr[2];
#pragma unroll
            for (int ni = 0; ni < 2; ++ni)
                bfr[ni] = *(const bf16x8*)&As[boff + c * 2048 + ni * 128];
#pragma unroll
            for (int mi = 0; mi < 2; ++mi)
#pragma unroll
                for (int ni = 0; ni < 2; ++ni)
                    acc[c][mi][ni] = __builtin_amdgcn_mfma_f32_16x16x32_bf16(
                        af[mi], bfr[ni], acc[c][mi][ni], 0, 0, 0);
        }
        __builtin_amdgcn_s_barrier();   // buf (kt&1) free for overwrite at kt+1
        asm volatile("" ::: "memory");
    }

    // ---- blend: all 48 mini-MFMAs upfront, results held in registers ----
    bf16x8 wf[2];
#pragma unroll
    for (int ni = 0; ni < 2; ++ni)
        wf[ni] = *(const bf16x8*)&wtsB[(((vtile * 4 + kq) * 64) +
                                        wavev * 32 + ni * 16 + l15) * 8];

    int bframe = ((btile * 4 + kq) * 64 + waveb * 32 + l15) * 8;  // + mi*128

    float res3[2][2][4][3];    // [mi][ni][r][m]
#pragma unroll
    for (int mi = 0; mi < 2; ++mi) {
#pragma unroll
        for (int m = 0; m < 3; ++m) {
            f32x4 T[4][2] = {};
#pragma unroll
            for (int c4 = 0; c4 < 4; ++c4) {
                int mc = m * 4 + c4;
                bf16x8 gf = *(const bf16x8*)&G2B[mc * 32768 + bframe + mi * 128];
#pragma unroll
                for (int ni = 0; ni < 2; ++ni)
                    T[c4][ni] = __builtin_amdgcn_mfma_f32_16x16x32_bf16(
                        gf, wf[ni], T[c4][ni], 0, 0, 0);
            }
#pragma unroll
            for (int ni = 0; ni < 2; ++ni) {
#pragma unroll
                for (int r = 0; r < 4; ++r) {
                    int bl = waveb * 32 + mi * 16 + (kq << 2) + r;
                    int b  = btile * 64 + bl;
                    float x = acc[0][mi][ni][r];
                    float y = acc[1][mi][ni][r];
                    float z = acc[2][mi][ni][r];
                    res3[mi][ni][r][m] = T[3][ni][r] + T[0][ni][r] * x +
                                         T[1][ni][r] * y + T[2][ni][r] * z +
                                         trans[b * 3 + m];
                }
            }
        }
    }

    // ---- 2-pass LDS transpose + sector-dense non-temporal store ----
    int fvalid = (NV - vtile * 64) * 3;           // floats valid in this span
    if (fvalid > 192) fvalid = 192;
#pragma unroll
    for (int pass = 0; pass < 2; ++pass) {
        if (waveb == pass) {
            // this half's waves own rows pass*32 .. pass*32+31
#pragma unroll
            for (int mi = 0; mi < 2; ++mi) {
#pragma unroll
                for (int ni = 0; ni < 2; ++ni) {
                    int vl = wavev * 32 + ni * 16 + l15;
#pragma unroll
                    for (int r = 0; r < 4; ++r) {
                        int row = mi * 16 + (kq << 2) + r;   // 0..31
#pragma unroll
                        for (int m = 0; m < 3; ++m)
                            outs[row * 204 + vl * 3 + m] = res3[mi][ni][r][m];
                    }
                }
            }
        }
        __syncthreads();
        // readback: one full 768 B row per store instruction (48 lanes x
        // dwordx4); 8 rows per wave. nt -> no L2 read-allocate (RMW kill).
        if (lane < 48) {
            int fbase = lane * 4;
#pragma unroll
            for (int it = 0; it < 8; ++it) {
                int bl = wid * 8 + it;                       // 0..31
                int b  = btile * 64 + pass * 32 + bl;
                const float* src = &outs[bl * 204 + fbase];
                float* dst = &outp[(size_t)b * V3 + (size_t)vtile * 192 + fbase];
                if (fbase + 4 <= fvalid) {
                    f4u v = *(const f4u*)src;
                    __builtin_nontemporal_store(v, (f4u*)dst);
                } else {
#pragma unroll
                    for (int k2 = 0; k2 < 4; ++k2)
                        if (fbase + k2 < fvalid) dst[k2] = src[k2];
                }
            }
        }
        if (pass == 0) __syncthreads();   // protect rows before pass-1 overwrite
    }
}

extern "C" void kernel_launch(void* const* d_in, const int* in_sizes, int n_in,
                              void* d_out, int out_size, void* d_ws, size_t ws_size,
                              hipStream_t stream)
{
    const float* pose   = (const float*)d_in[0];
    const float* betas  = (const float*)d_in[1];
    const float* trans  = (const float*)d_in[2];
    const float* vtempl = (const float*)d_in[3];
    const float* shdirs = (const float*)d_in[4];
    const float* pdirs  = (const float*)d_in[5];
    const float* Jreg   = (const float*)d_in[6];
    const float* wts    = (const float*)d_in[7];
    float* out = (float*)d_out;
    char* ws = (char*)d_ws;

    float* Jc              = (float*)(ws);                      // 792 fl (4 KB)
    __hip_bfloat16* ABsw   = (__hip_bfloat16*)(ws + 4096);      // 229376 bf16
    __hip_bfloat16* G2B    = (__hip_bfloat16*)(ws + 462848);    // 393216 bf16
    __hip_bfloat16* wtsB   = (__hip_bfloat16*)(ws + 1249280);   // 221184 bf16
    __hip_bfloat16* pdBsw  = (__hip_bfloat16*)(ws + 1691648);   // 4644864 bf16

    // 3 dispatches total (was 5 + memset): kpre fuses kpack|kwB|k0.
    hipLaunchKernelGGL(kpre, dim3(2400), dim3(256), 0, stream,
                       pdirs, shdirs, vtempl, wts, Jreg, pdBsw, wtsB, Jc);
    hipLaunchKernelGGL(k1, dim3(NB / 4), dim3(256), 0, stream,
                       pose, betas, trans, Jc, ABsw, G2B, out);
    hipLaunchKernelGGL(k2g, dim3(108, 16), dim3(256), 0, stream,
                       pdBsw, ABsw, G2B, wtsB, trans, out);
}

// Round 10
// 181.773 us; speedup vs baseline: 1.1322x; 1.1322x over previous
//
#include <hip/hip_runtime.h>
#include <hip/hip_bf16.h>

#define NJ 24
#define NV 6890
#define NB 1024
#define V3 (NV*3)         // 20670 floats per batch in out
#define JTR_OFF (NB*NV*3)

typedef __attribute__((ext_vector_type(8))) short bf16x8;
typedef __attribute__((ext_vector_type(4))) float f32x4;
typedef float f4u __attribute__((ext_vector_type(4), aligned(4)));

__constant__ int c_par[NJ] = {-1,0,0,0,1,2,3,4,5,6,7,8,9,9,9,12,13,14,16,17,18,19,20,21};

// ---------------------------------------------------------------------------
// kpre: fused preprocessing — one dispatch replaces kpack + kwB + k0.
//   bid <  2268 : kpack  (pdBsw build, 580608 chunks)
//   bid <  2376 : kwB    (wtsB build, 27648 chunks)
//   bid <  2472 : k0     (joint regressor fold; 96 blocks = 24 joints x 4
//                         v-quarters, stride-1024, atomicAdd into zeroed Jc
//                         — round-9's 24-block version lost 4x parallelism
//                         and added a ~20 us straggler tail; reverted.)
// ---------------------------------------------------------------------------
__global__ void kpre(const float* __restrict__ pdirs, const float* __restrict__ shdirs,
                     const float* __restrict__ vtempl, const float* __restrict__ wts,
                     const float* __restrict__ Jreg,
                     __hip_bfloat16* __restrict__ pdBsw, __hip_bfloat16* __restrict__ wtsB,
                     float* __restrict__ Jc)
{
    __shared__ float red[4][33];
    int bid = blockIdx.x;

    if (bid < 2268) {
        // ---- kpack: chunk cid = (((vtile*7+kt)*3+c)*4+kq)*64+v64, 8 k each
        int cid = bid * 256 + threadIdx.x;   // < 580608
        int v64 = cid & 63;
        int t = cid >> 6;
        int kq = t & 3; t >>= 2;
        int c = t % 3; t /= 3;
        int kt = t % 7;
        int vt = t / 7;
        int v = vt * 64 + v64;

        ushort tmp[8] __attribute__((aligned(16)));
#pragma unroll
        for (int j = 0; j < 8; ++j) {
            int k = kt * 32 + kq * 8 + j;
            float val = 0.0f;
            if (v < NV) {
                if (k < 207)       val = pdirs[(v * 3 + c) * 207 + k];
                else if (k < 217)  val = shdirs[(v * 3 + c) * 10 + (k - 207)];
                else if (k == 217) val = vtempl[v * 3 + c];
            }
            __hip_bfloat16 h = __float2bfloat16(val);
            tmp[j] = *(ushort*)&h;
        }
        ((float4*)pdBsw)[cid] = *(const float4*)tmp;
    } else if (bid < 2376) {
        // ---- kwB: chunk = (vtile*4 + kq)*64 + v64, 8 j each, K=32
        int t = (bid - 2268) * 256 + threadIdx.x;     // < 27648
        int v64 = t & 63;
        int kq = (t >> 6) & 3;
        int vt = t >> 8;
        int v = vt * 64 + v64;

        ushort tmp[8] __attribute__((aligned(16)));
#pragma unroll
        for (int j8 = 0; j8 < 8; ++j8) {
            int j = kq * 8 + j8;
            float val = (v < NV && j < NJ) ? wts[v * NJ + j] : 0.0f;
            __hip_bfloat16 h = __float2bfloat16(val);
            tmp[j8] = *(ushort*)&h;
        }
        ((float4*)wtsB)[t] = *(const float4*)tmp;
    } else {
        // ---- k0: Jc[j][c][s] — s<10: Jreg@shapedirs, s=10: Jreg@tmpl
        int rem = bid - 2376;    // 0..95
        int j = rem >> 2;        // 0..23
        int q = rem & 3;         // v-quarter
        float acc[33];
#pragma unroll
        for (int i = 0; i < 33; ++i) acc[i] = 0.0f;

        for (int v = q * 256 + threadIdx.x; v < NV; v += 1024) {
            float r = Jreg[j * NV + v];
#pragma unroll
            for (int c = 0; c < 3; ++c) {
                acc[c * 11 + 10] += r * vtempl[v * 3 + c];
                const float* sd = &shdirs[(v * 3 + c) * 10];
#pragma unroll
                for (int s = 0; s < 10; ++s) acc[c * 11 + s] += r * sd[s];
            }
        }
#pragma unroll
        for (int i = 0; i < 33; ++i) {
            float x = acc[i];
            for (int o = 32; o > 0; o >>= 1) x += __shfl_down(x, o, 64);
            acc[i] = x;
        }
        int w = threadIdx.x >> 6, l = threadIdx.x & 63;
        if (l == 0) {
#pragma unroll
            for (int i = 0; i < 33; ++i) red[w][i] = acc[i];
        }
        __syncthreads();
        if (threadIdx.x < 33) {
            float s = red[0][threadIdx.x] + red[1][threadIdx.x] +
                      red[2][threadIdx.x] + red[3][threadIdx.x];
            atomicAdd(&Jc[j * 33 + threadIdx.x], s);
        }
    }
}

// ---------------------------------------------------------------------------
// k1: Rodrigues, A (bf16, swizzled), th_j, kinematic chain, G2B (bf16,
// A-operand swizzled, 12 components), th_jtr. One wave/batch, 4 batches/block.
// ABsw chunk: ((btile*7 + kt)*4 + kq)*64 + b64, 8 k each.
// G2B[mc] chunk: ((btile*4 + jq)*64 + b64)*8 + j7, mc stride 32768 elements.
// ---------------------------------------------------------------------------
__device__ __forceinline__ void writeA(__hip_bfloat16* ABsw, int b, int k, float val)
{
    int btile = b >> 6, b6 = b & 63, kt = k >> 5, kq = (k >> 3) & 3, j = k & 7;
    __hip_bfloat16 h = __float2bfloat16(val);
    ABsw[((((btile * 7) + kt) * 4 + kq) * 64 + b6) * 8 + j] = h;
}

__global__ void k1(const float* __restrict__ pose, const float* __restrict__ betas,
                   const float* __restrict__ trans, const float* __restrict__ Jc,
                   __hip_bfloat16* __restrict__ ABsw, __hip_bfloat16* __restrict__ G2B,
                   float* __restrict__ out)
{
    __shared__ float rots[4][NJ][9];
    __shared__ float thj [4][NJ][3];
    __shared__ float res [4][NJ][16];

    int w = threadIdx.x >> 6;
    int l = threadIdx.x & 63;
    int b = blockIdx.x * 4 + w;

    if (l < NJ) {
        int j = l;
        float ax = pose[b * 72 + j * 3 + 0];
        float ay = pose[b * 72 + j * 3 + 1];
        float az = pose[b * 72 + j * 3 + 2];
        float theta = sqrtf(ax * ax + ay * ay + az * az + 1e-8f);
        float inv = 1.0f / theta;
        float kx = ax * inv, ky = ay * inv, kz = az * inv;
        float c = cosf(theta), s = sinf(theta), mc = 1.0f - c;
        float R[9];
        R[0] = 1.0f - mc * (ky * ky + kz * kz);
        R[1] = -s * kz + mc * (kx * ky);
        R[2] =  s * ky + mc * (kx * kz);
        R[3] =  s * kz + mc * (kx * ky);
        R[4] = 1.0f - mc * (kx * kx + kz * kz);
        R[5] = -s * kx + mc * (ky * kz);
        R[6] = -s * ky + mc * (kx * kz);
        R[7] =  s * kx + mc * (ky * kz);
        R[8] = 1.0f - mc * (kx * kx + ky * ky);
#pragma unroll
        for (int e = 0; e < 9; ++e) rots[w][j][e] = R[e];
        if (j >= 1) {
            int base = (j - 1) * 9;
#pragma unroll
            for (int e = 0; e < 9; ++e) {
                float val = R[e] - ((e == 0 || e == 4 || e == 8) ? 1.0f : 0.0f);
                writeA(ABsw, b, base + e, val);
            }
        }
#pragma unroll
        for (int c3 = 0; c3 < 3; ++c3) {
            float acc = Jc[(j * 3 + c3) * 11 + 10];
#pragma unroll
            for (int s10 = 0; s10 < 10; ++s10)
                acc += Jc[(j * 3 + c3) * 11 + s10] * betas[b * 10 + s10];
            thj[w][j][c3] = acc;
        }
    } else if (l < 41) {
        int k = 207 + (l - 24);
        float val;
        if (l < 34)       val = betas[b * 10 + (l - 24)];
        else if (l == 34) val = 1.0f;
        else              val = 0.0f;
        writeA(ABsw, b, k, val);
    }
    __syncthreads();

    if (l < 16) {
        int m = l >> 2, n = l & 3;
        float v;
        if (m < 3) v = (n < 3) ? rots[w][0][m * 3 + n] : thj[w][0][m];
        else       v = (n == 3) ? 1.0f : 0.0f;
        res[w][0][l] = v;
    }
    __syncthreads();
#pragma unroll
    for (int i = 1; i < NJ; ++i) {
        int p = c_par[i];
        if (l < 16) {
            int m = l >> 2, n = l & 3;
            float acc = 0.0f;
#pragma unroll
            for (int k3 = 0; k3 < 3; ++k3) {
                float relkn = (n < 3) ? rots[w][i][k3 * 3 + n]
                                      : (thj[w][i][k3] - thj[w][p][k3]);
                acc += res[w][p][m * 4 + k3] * relkn;
            }
            if (n == 3) acc += res[w][p][m * 4 + 3];
            res[w][i][l] = acc;
        }
        __syncthreads();
    }

    if (l < NJ) {
        int j = l;
#pragma unroll
        for (int c3 = 0; c3 < 3; ++c3)
            out[JTR_OFF + b * 72 + j * 3 + c3] = res[w][j][c3 * 4 + 3] + trans[b * 3 + c3];
    }
    // G2B: 12 components mc = m*4+n, K=32 (j=24..31 zero), bf16 A-operand swizzle
    for (int k = l; k < 384; k += 64) {
        int mc = k >> 5, j = k & 31;
        int m = mc >> 2, n = mc & 3;
        float v = 0.0f;
        if (j < NJ) {
            if (n < 3) v = res[w][j][m * 4 + n];
            else v = res[w][j][m * 4 + 3] - (res[w][j][m * 4 + 0] * thj[w][j][0] +
                                             res[w][j][m * 4 + 1] * thj[w][j][1] +
                                             res[w][j][m * 4 + 2] * thj[w][j][2]);
        }
        __hip_bfloat16 h = __float2bfloat16(v);
        G2B[mc * 32768 + ((((b >> 6) * 4) + (j >> 3)) * 64 + (b & 63)) * 8 + (j & 7)] = h;
    }
}

// ---------------------------------------------------------------------------
// helper: 16B global -> LDS direct (DMA), wave-uniform LDS base + lane*16.
// ---------------------------------------------------------------------------
__device__ __forceinline__ void gld16(const void* g, void* l)
{
    __builtin_amdgcn_global_load_lds(
        (const __attribute__((address_space(1))) void*)g,
        (__attribute__((address_space(3))) void*)l, 16, 0, 0);
}

// ---------------------------------------------------------------------------
// k2g: fused pose-GEMM + MFMA blend.  A = batches (M), B = verts (N).
// Block: 64b x 64v x 3c, 4 waves (2x2), K-loop 7 x 32, mfma 16x16x32 bf16.
// v9 == round-8 structure exactly (nt-store reverted: 186.4 us measured).
// K-loop: double-buffered global_load_lds + raw s_barrier + counted
// vmcnt(4) — next tile's loads stay in flight across barriers.
// XCD remap (T1, +5 us): lin=(wgid&7)*216+(wgid>>3).
// Store path: blend(+trans) -> [32][204] f32 LDS tile, 2 passes; each
// 768B batch-row stored by 48 lanes x dwordx4 per instruction (sector-
// dense; TCC does masked sector writes with no cross-instruction merge).
// ---------------------------------------------------------------------------
__launch_bounds__(256, 3)
__global__ void k2g(const __hip_bfloat16* __restrict__ pdBsw,
                    const __hip_bfloat16* __restrict__ ABsw,
                    const __hip_bfloat16* __restrict__ G2B,
                    const __hip_bfloat16* __restrict__ wtsB,
                    const float* __restrict__ trans,
                    float* __restrict__ outp)
{
    // 2 x 16KB double-buffer (As 12KB + Bs 4KB each); epilogue outs tile
    // ([32][204] f32 = 26112B) overlays after the K-loop's final barrier.
    __shared__ __align__(16) char smem[2 * 16384];
    float* outs = (float*)smem;

    int tid = threadIdx.x;
    // XCD-aware remap: 1728 blocks = 8 XCDs x 216.
    int wgid = blockIdx.y * 108 + blockIdx.x;
    int lin  = (wgid & 7) * 216 + (wgid >> 3);
    int vtile = lin >> 4;        // 0..107
    int btile = lin & 15;        // 0..15
    int wid = tid >> 6, lane = tid & 63;
    int waveb = wid & 1, wavev = wid >> 1;
    int kq = lane >> 4, l15 = lane & 15;

    // stage one K-tile (As: 768 chunks, Bs: 256 chunks of 16B) into buf kb.
    auto stage = [&](int kb, int kt) {
        char* dst = smem + kb * 16384;
        const ushort* gA = (const ushort*)pdBsw + (size_t)(vtile * 7 + kt) * 6144;
        const ushort* gB = (const ushort*)ABsw  + (size_t)(btile * 7 + kt) * 2048;
#pragma unroll
        for (int i = 0; i < 3; ++i)
            gld16(gA + (i * 256 + wid * 64 + lane) * 8, dst + i * 4096 + wid * 1024);
        gld16(gB + (wid * 64 + lane) * 8, dst + 12288 + wid * 1024);
    };

    f32x4 acc[3][2][2] = {};   // [c][mi=b-sub][ni=v-sub]

    int aoff = (kq * 64 + waveb * 32 + l15) * 8;      // batch frag (Bs) + mi*128
    int boff = (kq * 64 + wavev * 32 + l15) * 8;      // vert frag (As) + ni*128 + c*2048

    stage(0, 0);
    for (int kt = 0; kt < 7; ++kt) {
        if (kt < 6) {
            stage((kt + 1) & 1, kt + 1);
            asm volatile("s_waitcnt vmcnt(4)" ::: "memory");  // cur tile landed
        } else {
            asm volatile("s_waitcnt vmcnt(0)" ::: "memory");
        }
        __builtin_amdgcn_s_barrier();
        asm volatile("" ::: "memory");

        const ushort* As = (const ushort*)(smem + (kt & 1) * 16384);
        const ushort* Bs = As + 6144;   // +12288 bytes

        bf16x8 af[2];
#pragma unroll
        for (int mi = 0; mi < 2; ++mi)
            af[mi] = *(const bf16x8*)&Bs[aoff + mi * 128];
#pragma unroll
        for (int c = 0; c < 3; ++c) {
            bf16x8 bfr[2];
#pragma unroll
            for (int ni = 0; ni < 2; ++ni)
                bfr[ni] = *(const bf16x8*)&As[boff + c * 2048 + ni * 128];
#pragma unroll
            for (int mi = 0; mi < 2; ++mi)
#pragma unroll
                for (int ni = 0; ni < 2; ++ni)
                    acc[c][mi][ni] = __builtin_amdgcn_mfma_f32_16x16x32_bf16(
                        af[mi], bfr[ni], acc[c][mi][ni], 0, 0, 0);
        }
        __builtin_amdgcn_s_barrier();   // buf (kt&1) free for overwrite at kt+1
        asm volatile("" ::: "memory");
    }

    // ---- blend: all 48 mini-MFMAs upfront, results held in registers ----
    bf16x8 wf[2];
#pragma unroll
    for (int ni = 0; ni < 2; ++ni)
        wf[ni] = *(const bf16x8*)&wtsB[(((vtile * 4 + kq) * 64) +
                                        wavev * 32 + ni * 16 + l15) * 8];

    int bframe = ((btile * 4 + kq) * 64 + waveb * 32 + l15) * 8;  // + mi*128

    float res3[2][2][4][3];    // [mi][ni][r][m]
#pragma unroll
    for (int mi = 0; mi < 2; ++mi) {
#pragma unroll
        for (int m = 0; m < 3; ++m) {
            f32x4 T[4][2] = {};
#pragma unroll
            for (int c4 = 0; c4 < 4; ++c4) {
                int mc = m * 4 + c4;
                bf16x8 gf = *(const bf16x8*)&G2B[mc * 32768 + bframe + mi * 128];
#pragma unroll
                for (int ni = 0; ni < 2; ++ni)
                    T[c4][ni] = __builtin_amdgcn_mfma_f32_16x16x32_bf16(
                        gf, wf[ni], T[c4][ni], 0, 0, 0);
            }
#pragma unroll
            for (int ni = 0; ni < 2; ++ni) {
#pragma unroll
                for (int r = 0; r < 4; ++r) {
                    int bl = waveb * 32 + mi * 16 + (kq << 2) + r;
                    int b  = btile * 64 + bl;
                    float x = acc[0][mi][ni][r];
                    float y = acc[1][mi][ni][r];
                    float z = acc[2][mi][ni][r];
                    res3[mi][ni][r][m] = T[3][ni][r] + T[0][ni][r] * x +
                                         T[1][ni][r] * y + T[2][ni][r] * z +
                                         trans[b * 3 + m];
                }
            }
        }
    }

    // ---- 2-pass LDS transpose + sector-dense store ----
    int fvalid = (NV - vtile * 64) * 3;           // floats valid in this span
    if (fvalid > 192) fvalid = 192;
#pragma unroll
    for (int pass = 0; pass < 2; ++pass) {
        if (waveb == pass) {
            // this half's waves own rows pass*32 .. pass*32+31
#pragma unroll
            for (int mi = 0; mi < 2; ++mi) {
#pragma unroll
                for (int ni = 0; ni < 2; ++ni) {
                    int vl = wavev * 32 + ni * 16 + l15;
#pragma unroll
                    for (int r = 0; r < 4; ++r) {
                        int row = mi * 16 + (kq << 2) + r;   // 0..31
#pragma unroll
                        for (int m = 0; m < 3; ++m)
                            outs[row * 204 + vl * 3 + m] = res3[mi][ni][r][m];
                    }
                }
            }
        }
        __syncthreads();
        // readback: one full 768 B row per store instruction (48 lanes x
        // dwordx4); 8 rows per wave.
        if (lane < 48) {
            int fbase = lane * 4;
#pragma unroll
            for (int it = 0; it < 8; ++it) {
                int bl = wid * 8 + it;                       // 0..31
                int b  = btile * 64 + pass * 32 + bl;
                const float* src = &outs[bl * 204 + fbase];
                float* dst = &outp[(size_t)b * V3 + (size_t)vtile * 192 + fbase];
                if (fbase + 4 <= fvalid) {
                    *(f4u*)dst = *(const f4u*)src;
                } else {
#pragma unroll
                    for (int k2 = 0; k2 < 4; ++k2)
                        if (fbase + k2 < fvalid) dst[k2] = src[k2];
                }
            }
        }
        if (pass == 0) __syncthreads();   // protect rows before pass-1 overwrite
    }
}

extern "C" void kernel_launch(void* const* d_in, const int* in_sizes, int n_in,
                              void* d_out, int out_size, void* d_ws, size_t ws_size,
                              hipStream_t stream)
{
    const float* pose   = (const float*)d_in[0];
    const float* betas  = (const float*)d_in[1];
    const float* trans  = (const float*)d_in[2];
    const float* vtempl = (const float*)d_in[3];
    const float* shdirs = (const float*)d_in[4];
    const float* pdirs  = (const float*)d_in[5];
    const float* Jreg   = (const float*)d_in[6];
    const float* wts    = (const float*)d_in[7];
    float* out = (float*)d_out;
    char* ws = (char*)d_ws;

    float* Jc              = (float*)(ws);                      // 792 fl (4 KB)
    __hip_bfloat16* ABsw   = (__hip_bfloat16*)(ws + 4096);      // 229376 bf16
    __hip_bfloat16* G2B    = (__hip_bfloat16*)(ws + 462848);    // 393216 bf16
    __hip_bfloat16* wtsB   = (__hip_bfloat16*)(ws + 1249280);   // 221184 bf16
    __hip_bfloat16* pdBsw  = (__hip_bfloat16*)(ws + 1691648);   // 4644864 bf16

    // 4 dispatches (was 6): memset + kpre (kpack|kwB|k0 fused) + k1 + k2g.
    hipMemsetAsync(Jc, 0, NJ * 33 * sizeof(float), stream);
    hipLaunchKernelGGL(kpre, dim3(2472), dim3(256), 0, stream,
                       pdirs, shdirs, vtempl, wts, Jreg, pdBsw, wtsB, Jc);
    hipLaunchKernelGGL(k1, dim3(NB / 4), dim3(256), 0, stream,
                       pose, betas, trans, Jc, ABsw, G2B, out);
    hipLaunchKernelGGL(k2g, dim3(108, 16), dim3(256), 0, stream,
                       pdBsw, ABsw, G2B, wtsB, trans, out);
}

// Round 11
// 175.747 us; speedup vs baseline: 1.1710x; 1.0343x over previous
//
#include <hip/hip_runtime.h>
#include <hip/hip_bf16.h>

#define NJ 24
#define NV 6890
#define NB 1024
#define V3 (NV*3)         // 20670 floats per batch in out
#define JTR_OFF (NB*NV*3)

typedef __attribute__((ext_vector_type(8))) short bf16x8;
typedef __attribute__((ext_vector_type(4))) float f32x4;
typedef float f4u __attribute__((ext_vector_type(4), aligned(4)));

__constant__ int c_par[NJ] = {-1,0,0,0,1,2,3,4,5,6,7,8,9,9,9,12,13,14,16,17,18,19,20,21};

// ---------------------------------------------------------------------------
// kpre: fused preprocessing — one dispatch replaces kpack + kwB + k0.
//   bid <  2268 : kpack  (pdBsw build, 580608 chunks)
//   bid <  2376 : kwB    (wtsB build, 27648 chunks)
//   bid <  2472 : k0     (joint regressor fold; 96 blocks = 24 joints x 4
//                         v-quarters, stride-1024, atomicAdd into zeroed Jc)
// v10: kpack loads vectorized. Old: 8 scalar dword loads/chunk (4.6M total,
// hipcc can't merge — 207-float rows are only 4B-aligned). New: 2 unaligned
// f4u loads/chunk on the 26/28 k-positions fully inside pdirs (s+8<=207) or
// fully inside shdirs (s==208); boundary chunks keep the scalar path.
// ---------------------------------------------------------------------------
__global__ void kpre(const float* __restrict__ pdirs, const float* __restrict__ shdirs,
                     const float* __restrict__ vtempl, const float* __restrict__ wts,
                     const float* __restrict__ Jreg,
                     __hip_bfloat16* __restrict__ pdBsw, __hip_bfloat16* __restrict__ wtsB,
                     float* __restrict__ Jc)
{
    __shared__ float red[4][33];
    int bid = blockIdx.x;

    if (bid < 2268) {
        // ---- kpack: chunk cid = (((vtile*7+kt)*3+c)*4+kq)*64+v64, 8 k each
        int cid = bid * 256 + threadIdx.x;   // < 580608
        int v64 = cid & 63;
        int t = cid >> 6;
        int kq = t & 3; t >>= 2;
        int c = t % 3; t /= 3;
        int kt = t % 7;
        int vt = t / 7;
        int v = vt * 64 + v64;
        int s = kt * 32 + kq * 8;            // chunk k-base

        ushort tmp[8] __attribute__((aligned(16)));
        if (v < NV && s + 8 <= 207) {
            // fast path: 8 consecutive pdirs floats via 2 unaligned f4u loads
            const float* row = &pdirs[(v * 3 + c) * 207 + s];
            f4u lo = *(const f4u*)row;
            f4u hi = *(const f4u*)(row + 4);
#pragma unroll
            for (int j = 0; j < 4; ++j) {
                __hip_bfloat16 h0 = __float2bfloat16(lo[j]);
                __hip_bfloat16 h1 = __float2bfloat16(hi[j]);
                tmp[j]     = *(ushort*)&h0;
                tmp[j + 4] = *(ushort*)&h1;
            }
        } else if (v < NV && s == 208) {
            // pure-shdirs chunk: k 208..215 -> sd[1..8]
            const float* sd = &shdirs[(v * 3 + c) * 10];
            f4u lo = *(const f4u*)(sd + 1);
            f4u hi = *(const f4u*)(sd + 5);
#pragma unroll
            for (int j = 0; j < 4; ++j) {
                __hip_bfloat16 h0 = __float2bfloat16(lo[j]);
                __hip_bfloat16 h1 = __float2bfloat16(hi[j]);
                tmp[j]     = *(ushort*)&h0;
                tmp[j + 4] = *(ushort*)&h1;
            }
        } else {
            // boundary / tail chunks: original scalar path
#pragma unroll
            for (int j = 0; j < 8; ++j) {
                int k = s + j;
                float val = 0.0f;
                if (v < NV) {
                    if (k < 207)       val = pdirs[(v * 3 + c) * 207 + k];
                    else if (k < 217)  val = shdirs[(v * 3 + c) * 10 + (k - 207)];
                    else if (k == 217) val = vtempl[v * 3 + c];
                }
                __hip_bfloat16 h = __float2bfloat16(val);
                tmp[j] = *(ushort*)&h;
            }
        }
        ((float4*)pdBsw)[cid] = *(const float4*)tmp;
    } else if (bid < 2376) {
        // ---- kwB: chunk = (vtile*4 + kq)*64 + v64, 8 j each, K=32
        int t = (bid - 2268) * 256 + threadIdx.x;     // < 27648
        int v64 = t & 63;
        int kq = (t >> 6) & 3;
        int vt = t >> 8;
        int v = vt * 64 + v64;

        ushort tmp[8] __attribute__((aligned(16)));
#pragma unroll
        for (int j8 = 0; j8 < 8; ++j8) {
            int j = kq * 8 + j8;
            float val = (v < NV && j < NJ) ? wts[v * NJ + j] : 0.0f;
            __hip_bfloat16 h = __float2bfloat16(val);
            tmp[j8] = *(ushort*)&h;
        }
        ((float4*)wtsB)[t] = *(const float4*)tmp;
    } else {
        // ---- k0: Jc[j][c][s] — s<10: Jreg@shapedirs, s=10: Jreg@tmpl
        int rem = bid - 2376;    // 0..95
        int j = rem >> 2;        // 0..23
        int q = rem & 3;         // v-quarter
        float acc[33];
#pragma unroll
        for (int i = 0; i < 33; ++i) acc[i] = 0.0f;

        for (int v = q * 256 + threadIdx.x; v < NV; v += 1024) {
            float r = Jreg[j * NV + v];
#pragma unroll
            for (int c = 0; c < 3; ++c) {
                acc[c * 11 + 10] += r * vtempl[v * 3 + c];
                const float* sd = &shdirs[(v * 3 + c) * 10];
#pragma unroll
                for (int s = 0; s < 10; ++s) acc[c * 11 + s] += r * sd[s];
            }
        }
#pragma unroll
        for (int i = 0; i < 33; ++i) {
            float x = acc[i];
            for (int o = 32; o > 0; o >>= 1) x += __shfl_down(x, o, 64);
            acc[i] = x;
        }
        int w = threadIdx.x >> 6, l = threadIdx.x & 63;
        if (l == 0) {
#pragma unroll
            for (int i = 0; i < 33; ++i) red[w][i] = acc[i];
        }
        __syncthreads();
        if (threadIdx.x < 33) {
            float s = red[0][threadIdx.x] + red[1][threadIdx.x] +
                      red[2][threadIdx.x] + red[3][threadIdx.x];
            atomicAdd(&Jc[j * 33 + threadIdx.x], s);
        }
    }
}

// ---------------------------------------------------------------------------
// k1: Rodrigues, A (bf16, swizzled), th_j, kinematic chain, G2B (bf16,
// A-operand swizzled, 12 components), th_jtr. One wave/batch, 4 batches/block.
// ABsw chunk: ((btile*7 + kt)*4 + kq)*64 + b64, 8 k each.
// G2B[mc] chunk: ((btile*4 + jq)*64 + b64)*8 + j7, mc stride 32768 elements.
// ---------------------------------------------------------------------------
__device__ __forceinline__ void writeA(__hip_bfloat16* ABsw, int b, int k, float val)
{
    int btile = b >> 6, b6 = b & 63, kt = k >> 5, kq = (k >> 3) & 3, j = k & 7;
    __hip_bfloat16 h = __float2bfloat16(val);
    ABsw[((((btile * 7) + kt) * 4 + kq) * 64 + b6) * 8 + j] = h;
}

__global__ void k1(const float* __restrict__ pose, const float* __restrict__ betas,
                   const float* __restrict__ trans, const float* __restrict__ Jc,
                   __hip_bfloat16* __restrict__ ABsw, __hip_bfloat16* __restrict__ G2B,
                   float* __restrict__ out)
{
    __shared__ float rots[4][NJ][9];
    __shared__ float thj [4][NJ][3];
    __shared__ float res [4][NJ][16];

    int w = threadIdx.x >> 6;
    int l = threadIdx.x & 63;
    int b = blockIdx.x * 4 + w;

    if (l < NJ) {
        int j = l;
        float ax = pose[b * 72 + j * 3 + 0];
        float ay = pose[b * 72 + j * 3 + 1];
        float az = pose[b * 72 + j * 3 + 2];
        float theta = sqrtf(ax * ax + ay * ay + az * az + 1e-8f);
        float inv = 1.0f / theta;
        float kx = ax * inv, ky = ay * inv, kz = az * inv;
        float c = cosf(theta), s = sinf(theta), mc = 1.0f - c;
        float R[9];
        R[0] = 1.0f - mc * (ky * ky + kz * kz);
        R[1] = -s * kz + mc * (kx * ky);
        R[2] =  s * ky + mc * (kx * kz);
        R[3] =  s * kz + mc * (kx * ky);
        R[4] = 1.0f - mc * (kx * kx + kz * kz);
        R[5] = -s * kx + mc * (ky * kz);
        R[6] = -s * ky + mc * (kx * kz);
        R[7] =  s * kx + mc * (ky * kz);
        R[8] = 1.0f - mc * (kx * kx + ky * ky);
#pragma unroll
        for (int e = 0; e < 9; ++e) rots[w][j][e] = R[e];
        if (j >= 1) {
            int base = (j - 1) * 9;
#pragma unroll
            for (int e = 0; e < 9; ++e) {
                float val = R[e] - ((e == 0 || e == 4 || e == 8) ? 1.0f : 0.0f);
                writeA(ABsw, b, base + e, val);
            }
        }
#pragma unroll
        for (int c3 = 0; c3 < 3; ++c3) {
            float acc = Jc[(j * 3 + c3) * 11 + 10];
#pragma unroll
            for (int s10 = 0; s10 < 10; ++s10)
                acc += Jc[(j * 3 + c3) * 11 + s10] * betas[b * 10 + s10];
            thj[w][j][c3] = acc;
        }
    } else if (l < 41) {
        int k = 207 + (l - 24);
        float val;
        if (l < 34)       val = betas[b * 10 + (l - 24)];
        else if (l == 34) val = 1.0f;
        else              val = 0.0f;
        writeA(ABsw, b, k, val);
    }
    __syncthreads();

    if (l < 16) {
        int m = l >> 2, n = l & 3;
        float v;
        if (m < 3) v = (n < 3) ? rots[w][0][m * 3 + n] : thj[w][0][m];
        else       v = (n == 3) ? 1.0f : 0.0f;
        res[w][0][l] = v;
    }
    __syncthreads();
#pragma unroll
    for (int i = 1; i < NJ; ++i) {
        int p = c_par[i];
        if (l < 16) {
            int m = l >> 2, n = l & 3;
            float acc = 0.0f;
#pragma unroll
            for (int k3 = 0; k3 < 3; ++k3) {
                float relkn = (n < 3) ? rots[w][i][k3 * 3 + n]
                                      : (thj[w][i][k3] - thj[w][p][k3]);
                acc += res[w][p][m * 4 + k3] * relkn;
            }
            if (n == 3) acc += res[w][p][m * 4 + 3];
            res[w][i][l] = acc;
        }
        __syncthreads();
    }

    if (l < NJ) {
        int j = l;
#pragma unroll
        for (int c3 = 0; c3 < 3; ++c3)
            out[JTR_OFF + b * 72 + j * 3 + c3] = res[w][j][c3 * 4 + 3] + trans[b * 3 + c3];
    }
    // G2B: 12 components mc = m*4+n, K=32 (j=24..31 zero), bf16 A-operand swizzle
    for (int k = l; k < 384; k += 64) {
        int mc = k >> 5, j = k & 31;
        int m = mc >> 2, n = mc & 3;
        float v = 0.0f;
        if (j < NJ) {
            if (n < 3) v = res[w][j][m * 4 + n];
            else v = res[w][j][m * 4 + 3] - (res[w][j][m * 4 + 0] * thj[w][j][0] +
                                             res[w][j][m * 4 + 1] * thj[w][j][1] +
                                             res[w][j][m * 4 + 2] * thj[w][j][2]);
        }
        __hip_bfloat16 h = __float2bfloat16(v);
        G2B[mc * 32768 + ((((b >> 6) * 4) + (j >> 3)) * 64 + (b & 63)) * 8 + (j & 7)] = h;
    }
}

// ---------------------------------------------------------------------------
// helper: 16B global -> LDS direct (DMA), wave-uniform LDS base + lane*16.
// ---------------------------------------------------------------------------
__device__ __forceinline__ void gld16(const void* g, void* l)
{
    __builtin_amdgcn_global_load_lds(
        (const __attribute__((address_space(1))) void*)g,
        (__attribute__((address_space(3))) void*)l, 16, 0, 0);
}

// ---------------------------------------------------------------------------
// k2g: fused pose-GEMM + MFMA blend.  A = batches (M), B = verts (N).
// Block: 64b x 64v x 3c, 4 waves (2x2), K-loop 7 x 32, mfma 16x16x32 bf16.
// == round-8/10 structure exactly (measured 181.8 total).
// K-loop: double-buffered global_load_lds + raw s_barrier + counted
// vmcnt(4) — next tile's loads stay in flight across barriers.
// XCD remap (T1, +5 us): lin=(wgid&7)*216+(wgid>>3).
// Store path: blend(+trans) -> [32][204] f32 LDS tile, 2 passes; each
// 768B batch-row stored by 48 lanes x dwordx4 per instruction (sector-
// dense; TCC does masked sector writes with no cross-instruction merge).
// ---------------------------------------------------------------------------
__launch_bounds__(256, 3)
__global__ void k2g(const __hip_bfloat16* __restrict__ pdBsw,
                    const __hip_bfloat16* __restrict__ ABsw,
                    const __hip_bfloat16* __restrict__ G2B,
                    const __hip_bfloat16* __restrict__ wtsB,
                    const float* __restrict__ trans,
                    float* __restrict__ outp)
{
    // 2 x 16KB double-buffer (As 12KB + Bs 4KB each); epilogue outs tile
    // ([32][204] f32 = 26112B) overlays after the K-loop's final barrier.
    __shared__ __align__(16) char smem[2 * 16384];
    float* outs = (float*)smem;

    int tid = threadIdx.x;
    // XCD-aware remap: 1728 blocks = 8 XCDs x 216.
    int wgid = blockIdx.y * 108 + blockIdx.x;
    int lin  = (wgid & 7) * 216 + (wgid >> 3);
    int vtile = lin >> 4;        // 0..107
    int btile = lin & 15;        // 0..15
    int wid = tid >> 6, lane = tid & 63;
    int waveb = wid & 1, wavev = wid >> 1;
    int kq = lane >> 4, l15 = lane & 15;

    // stage one K-tile (As: 768 chunks, Bs: 256 chunks of 16B) into buf kb.
    auto stage = [&](int kb, int kt) {
        char* dst = smem + kb * 16384;
        const ushort* gA = (const ushort*)pdBsw + (size_t)(vtile * 7 + kt) * 6144;
        const ushort* gB = (const ushort*)ABsw  + (size_t)(btile * 7 + kt) * 2048;
#pragma unroll
        for (int i = 0; i < 3; ++i)
            gld16(gA + (i * 256 + wid * 64 + lane) * 8, dst + i * 4096 + wid * 1024);
        gld16(gB + (wid * 64 + lane) * 8, dst + 12288 + wid * 1024);
    };

    f32x4 acc[3][2][2] = {};   // [c][mi=b-sub][ni=v-sub]

    int aoff = (kq * 64 + waveb * 32 + l15) * 8;      // batch frag (Bs) + mi*128
    int boff = (kq * 64 + wavev * 32 + l15) * 8;      // vert frag (As) + ni*128 + c*2048

    stage(0, 0);
    for (int kt = 0; kt < 7; ++kt) {
        if (kt < 6) {
            stage((kt + 1) & 1, kt + 1);
            asm volatile("s_waitcnt vmcnt(4)" ::: "memory");  // cur tile landed
        } else {
            asm volatile("s_waitcnt vmcnt(0)" ::: "memory");
        }
        __builtin_amdgcn_s_barrier();
        asm volatile("" ::: "memory");

        const ushort* As = (const ushort*)(smem + (kt & 1) * 16384);
        const ushort* Bs = As + 6144;   // +12288 bytes

        bf16x8 af[2];
#pragma unroll
        for (int mi = 0; mi < 2; ++mi)
            af[mi] = *(const bf16x8*)&Bs[aoff + mi * 128];
#pragma unroll
        for (int c = 0; c < 3; ++c) {
            bf16x8 bfr[2];
#pragma unroll
            for (int ni = 0; ni < 2; ++ni)
                bfr[ni] = *(const bf16x8*)&As[boff + c * 2048 + ni * 128];
#pragma unroll
            for (int mi = 0; mi < 2; ++mi)
#pragma unroll
                for (int ni = 0; ni < 2; ++ni)
                    acc[c][mi][ni] = __builtin_amdgcn_mfma_f32_16x16x32_bf16(
                        af[mi], bfr[ni], acc[c][mi][ni], 0, 0, 0);
        }
        __builtin_amdgcn_s_barrier();   // buf (kt&1) free for overwrite at kt+1
        asm volatile("" ::: "memory");
    }

    // ---- blend: all 48 mini-MFMAs upfront, results held in registers ----
    bf16x8 wf[2];
#pragma unroll
    for (int ni = 0; ni < 2; ++ni)
        wf[ni] = *(const bf16x8*)&wtsB[(((vtile * 4 + kq) * 64) +
                                        wavev * 32 + ni * 16 + l15) * 8];

    int bframe = ((btile * 4 + kq) * 64 + waveb * 32 + l15) * 8;  // + mi*128

    float res3[2][2][4][3];    // [mi][ni][r][m]
#pragma unroll
    for (int mi = 0; mi < 2; ++mi) {
#pragma unroll
        for (int m = 0; m < 3; ++m) {
            f32x4 T[4][2] = {};
#pragma unroll
            for (int c4 = 0; c4 < 4; ++c4) {
                int mc = m * 4 + c4;
                bf16x8 gf = *(const bf16x8*)&G2B[mc * 32768 + bframe + mi * 128];
#pragma unroll
                for (int ni = 0; ni < 2; ++ni)
                    T[c4][ni] = __builtin_amdgcn_mfma_f32_16x16x32_bf16(
                        gf, wf[ni], T[c4][ni], 0, 0, 0);
            }
#pragma unroll
            for (int ni = 0; ni < 2; ++ni) {
#pragma unroll
                for (int r = 0; r < 4; ++r) {
                    int bl = waveb * 32 + mi * 16 + (kq << 2) + r;
                    int b  = btile * 64 + bl;
                    float x = acc[0][mi][ni][r];
                    float y = acc[1][mi][ni][r];
                    float z = acc[2][mi][ni][r];
                    res3[mi][ni][r][m] = T[3][ni][r] + T[0][ni][r] * x +
                                         T[1][ni][r] * y + T[2][ni][r] * z +
                                         trans[b * 3 + m];
                }
            }
        }
    }

    // ---- 2-pass LDS transpose + sector-dense store ----
    int fvalid = (NV - vtile * 64) * 3;           // floats valid in this span
    if (fvalid > 192) fvalid = 192;
#pragma unroll
    for (int pass = 0; pass < 2; ++pass) {
        if (waveb == pass) {
            // this half's waves own rows pass*32 .. pass*32+31
#pragma unroll
            for (int mi = 0; mi < 2; ++mi) {
#pragma unroll
                for (int ni = 0; ni < 2; ++ni) {
                    int vl = wavev * 32 + ni * 16 + l15;
#pragma unroll
                    for (int r = 0; r < 4; ++r) {
                        int row = mi * 16 + (kq << 2) + r;   // 0..31
#pragma unroll
                        for (int m = 0; m < 3; ++m)
                            outs[row * 204 + vl * 3 + m] = res3[mi][ni][r][m];
                    }
                }
            }
        }
        __syncthreads();
        // readback: one full 768 B row per store instruction (48 lanes x
        // dwordx4); 8 rows per wave.
        if (lane < 48) {
            int fbase = lane * 4;
#pragma unroll
            for (int it = 0; it < 8; ++it) {
                int bl = wid * 8 + it;                       // 0..31
                int b  = btile * 64 + pass * 32 + bl;
                const float* src = &outs[bl * 204 + fbase];
                float* dst = &outp[(size_t)b * V3 + (size_t)vtile * 192 + fbase];
                if (fbase + 4 <= fvalid) {
                    *(f4u*)dst = *(const f4u*)src;
                } else {
#pragma unroll
                    for (int k2 = 0; k2 < 4; ++k2)
                        if (fbase + k2 < fvalid) dst[k2] = src[k2];
                }
            }
        }
        if (pass == 0) __syncthreads();   // protect rows before pass-1 overwrite
    }
}

extern "C" void kernel_launch(void* const* d_in, const int* in_sizes, int n_in,
                              void* d_out, int out_size, void* d_ws, size_t ws_size,
                              hipStream_t stream)
{
    const float* pose   = (const float*)d_in[0];
    const float* betas  = (const float*)d_in[1];
    const float* trans  = (const float*)d_in[2];
    const float* vtempl = (const float*)d_in[3];
    const float* shdirs = (const float*)d_in[4];
    const float* pdirs  = (const float*)d_in[5];
    const float* Jreg   = (const float*)d_in[6];
    const float* wts    = (const float*)d_in[7];
    float* out = (float*)d_out;
    char* ws = (char*)d_ws;

    float* Jc              = (float*)(ws);                      // 792 fl (4 KB)
    __hip_bfloat16* ABsw   = (__hip_bfloat16*)(ws + 4096);      // 229376 bf16
    __hip_bfloat16* G2B    = (__hip_bfloat16*)(ws + 462848);    // 393216 bf16
    __hip_bfloat16* wtsB   = (__hip_bfloat16*)(ws + 1249280);   // 221184 bf16
    __hip_bfloat16* pdBsw  = (__hip_bfloat16*)(ws + 1691648);   // 4644864 bf16

    // 4 dispatches: memset + kpre (kpack|kwB|k0 fused) + k1 + k2g.
    hipMemsetAsync(Jc, 0, NJ * 33 * sizeof(float), stream);
    hipLaunchKernelGGL(kpre, dim3(2472), dim3(256), 0, stream,
                       pdirs, shdirs, vtempl, wts, Jreg, pdBsw, wtsB, Jc);
    hipLaunchKernelGGL(k1, dim3(NB / 4), dim3(256), 0, stream,
                       pose, betas, trans, Jc, ABsw, G2B, out);
    hipLaunchKernelGGL(k2g, dim3(108, 16), dim3(256), 0, stream,
                       pdBsw, ABsw, G2B, wtsB, trans, out);
}